// Round 8
// baseline (246.318 us; speedup 1.0000x reference)
//
#include <hip/hip_runtime.h>
#include <hip/hip_bf16.h>
#include <hip/hip_cooperative_groups.h>

namespace cg = cooperative_groups;

#define BQ   16
#define BK2  32     // 2B
#define SEQ  256
#define HD   768
#define NROWS ((BQ + BK2) * SEQ)   // 12288
#define NUNITS (BQ * BK2 * 4)      // 2048 (i,j,sh) li units

typedef __attribute__((ext_vector_type(8))) short bf16x8;
typedef __attribute__((ext_vector_type(4))) float f32x4;

__device__ __forceinline__ void glds16(const unsigned short* g, unsigned short* l) {
    __builtin_amdgcn_global_load_lds(
        (const __attribute__((address_space(1))) unsigned int*)g,
        (__attribute__((address_space(3))) unsigned int*)l, 16, 0, 0);
}

// branch-free RNE fp32->bf16, packed two at a time
__device__ __forceinline__ unsigned int pack2_bf16(float a, float b) {
    unsigned ua = __float_as_uint(a), ub = __float_as_uint(b);
    ua += 0x7FFFu + ((ua >> 16) & 1u);
    ub += 0x7FFFu + ((ub >> 16) & 1u);
    return (ua >> 16) | (ub & 0xFFFF0000u);
}

// Single cooperative kernel: phase 1 = l2-normalize fp32 -> bf16 (+ zero out),
// grid.sync(), phase 2 = persistent loop over 2048 li units (R7's proven
// 40960-B body: 64s x 256t, 4 waves, glds + swizzled LDS, 1 atomicAdd/unit).
__global__ __launch_bounds__(256, 4) void fused_kernel(
    const float* __restrict__ q, const float* __restrict__ k,
    const float* __restrict__ g_ls, const float* __restrict__ g_ar,
    const int* __restrict__ q_mask, const int* __restrict__ k_mask,
    unsigned short* __restrict__ qn, unsigned short* __restrict__ kn,
    float* __restrict__ out, int nblocks)
{
    const int bid  = blockIdx.x;
    const int tid  = threadIdx.x;
    const int w    = tid >> 6, lane = tid & 63;
    const int ln   = lane & 15, lg = lane >> 4;

    __shared__ __align__(16) unsigned short As[64 * 64];   //  8 KB, swizzled
    __shared__ __align__(16) unsigned short Bs[256 * 64];  // 32 KB, swizzled
    // total LDS = 40960 B exactly; epilogue scratch reuses As after a barrier.

    // ---------------- phase 1: normalize, strided by global wave ----------
    if (bid == 0) { out[tid] = 0.f; out[tid + 256] = 0.f; }   // zero for atomics
    const int nwaves = nblocks * 4;
    for (int row = bid * 4 + w; row < NROWS; row += nwaves) {
        const float* src = (row < BQ * SEQ) ? q + (size_t)row * HD
                                            : k + (size_t)(row - BQ * SEQ) * HD;
        unsigned int* dst = (unsigned int*)((row < BQ * SEQ)
                              ? qn + (size_t)row * HD
                              : kn + (size_t)(row - BQ * SEQ) * HD);
        float4 v[3];
        float ss = 0.f;
#pragma unroll
        for (int c = 0; c < 3; ++c) {
            v[c] = ((const float4*)src)[lane + 64 * c];
            ss += v[c].x * v[c].x + v[c].y * v[c].y + v[c].z * v[c].z + v[c].w * v[c].w;
        }
#pragma unroll
        for (int m = 1; m < 64; m <<= 1) ss += __shfl_xor(ss, m, 64);
        float inv = rsqrtf(fmaxf(ss, 1e-24f));
#pragma unroll
        for (int c = 0; c < 3; ++c) {
            uint2 o = make_uint2(pack2_bf16(v[c].x * inv, v[c].y * inv),
                                 pack2_bf16(v[c].z * inv, v[c].w * inv));
            ((uint2*)dst)[lane + 64 * c] = o;
        }
    }

    cg::this_grid().sync();   // release qn/kn/out device-wide; acquire for phase 2

    // ---------------- phase 2: persistent li units ------------------------
    float a0 = g_ar[0];
    float alpha = (a0 > 0.f) ? a0 : 0.01f * a0;        // leaky_relu
    float scale = __expf(g_ls[0]);

    const int rl  = lane >> 3;
    const int gch = (lane & 7) ^ rl;   // swizzle: LDS slot (lane&7) <- chunk (lane&7)^(row&7)

    for (int unit = bid; unit < NUNITS; unit += nblocks) {
        const int sh = unit & 3, j = (unit >> 2) & 31, i = unit >> 7;

        const unsigned short* aq = qn + ((size_t)i * SEQ + sh * 64 + w * 8 + rl) * HD + gch * 8;
        const unsigned short* bq = kn + ((size_t)j * SEQ + w * 8 + rl) * HD + gch * 8;
        unsigned short* al = As + (w * 8) * 64;
        unsigned short* bl = Bs + (w * 8) * 64;

        f32x4 acc[4][4];
        const f32x4 zero4 = {0.f, 0.f, 0.f, 0.f};
#pragma unroll
        for (int a = 0; a < 4; ++a)
#pragma unroll
            for (int b = 0; b < 4; ++b) acc[a][b] = zero4;

        for (int kk = 0; kk < HD; kk += 64) {
            __syncthreads();                       // prev stage / scratch consumed
#pragma unroll
            for (int c = 0; c < 2; ++c)            // A rows 0..63
                glds16(aq + kk + c * (32 * HD), al + c * (32 * 64));
#pragma unroll
            for (int c = 0; c < 8; ++c)            // B rows 0..255
                glds16(bq + kk + c * (32 * HD), bl + c * (32 * 64));
            __syncthreads();                       // vmcnt drained before barrier
            const bf16x8* A8 = (const bf16x8*)As;
            const bf16x8* B8 = (const bf16x8*)Bs;
#pragma unroll
            for (int ks = 0; ks < 2; ++ks) {
                const int ch = (ks * 4 + lg) ^ (ln & 7);   // unswizzle
                bf16x8 af[4], bfr[4];
#pragma unroll
                for (int rm = 0; rm < 4; ++rm)
                    af[rm] = A8[(rm * 16 + ln) * 8 + ch];
#pragma unroll
                for (int cn = 0; cn < 4; ++cn)
                    bfr[cn] = B8[(w * 64 + cn * 16 + ln) * 8 + ch];
#pragma unroll
                for (int rm = 0; rm < 4; ++rm)
#pragma unroll
                    for (int cn = 0; cn < 4; ++cn)
                        acc[rm][cn] = __builtin_amdgcn_mfma_f32_16x16x32_bf16(
                            af[rm], bfr[cn], acc[rm][cn], 0, 0, 0);
            }
        }

        // k_mask for this lane's 4 t-columns (global, L2-hot)
        float kmv[4];
#pragma unroll
        for (int cn = 0; cn < 4; ++cn)
            kmv[cn] = (k_mask[j * SEQ + w * 64 + cn * 16 + ln] != 0) ? 1.f : 0.f;

        // epilogue: C/D layout col=ln (t), row=lg*4+r (s)
        __syncthreads();                    // As/Bs reads done; reuse As as scratch
        float* zs  = (float*)As;            // [64][4] Z partials per (srow, wt=w)
        float* wsc = zs + 256;              // [64][4] W partials

#pragma unroll
        for (int rm = 0; rm < 4; ++rm)
#pragma unroll
            for (int r = 0; r < 4; ++r) {
                int srow = rm * 16 + lg * 4 + r;          // s within unit's 64
                int s  = sh * 64 + srow;
                float ze = 0.f, we = 0.f;
#pragma unroll
                for (int cn = 0; cn < 4; ++cn) {
                    int t = w * 64 + cn * 16 + ln;        // global t (full 256)
                    float sim = acc[rm][cn][r];
                    int d = s - t; d = (d < 0) ? -d : d;
                    float wd = __expf(-alpha * (float)d);
                    float e  = kmv[cn] * __expf(sim * scale * wd);
                    ze += e;
                    we = fmaf(e, sim, we);
                }
#pragma unroll
                for (int m = 1; m < 16; m <<= 1) {        // reduce over t-16 lanes
                    ze += __shfl_xor(ze, m, 64);
                    we += __shfl_xor(we, m, 64);
                }
                if (ln == 0) { zs[srow * 4 + w] = ze; wsc[srow * 4 + w] = we; }
            }
        __syncthreads();

        // wave 0 finishes: combine 4 quarters, divide, q-mask, reduce 64 rows,
        // single fp32 atomicAdd per unit (cheap; R5 fences / R6 data-atomics
        // both regressed badly on gfx950's non-coherent per-XCD L2s)
        if (w == 0) {
            const float4 Z4 = ((const float4*)zs)[lane];
            const float4 W4 = ((const float4*)wsc)[lane];
            float Z = Z4.x + Z4.y + Z4.z + Z4.w;
            float W = W4.x + W4.y + W4.z + W4.w;
            float pt = (Z > 0.f) ? (W / Z) : 0.f;
            float part = pt * (float)q_mask[i * SEQ + sh * 64 + lane];
#pragma unroll
            for (int m = 1; m < 64; m <<= 1) part += __shfl_xor(part, m, 64);
            if (lane == 0) atomicAdd(&out[i * BK2 + j], part);
        }
    }
}

extern "C" void kernel_launch(void* const* d_in, const int* in_sizes, int n_in,
                              void* d_out, int out_size, void* d_ws, size_t ws_size,
                              hipStream_t stream) {
    const float* q  = (const float*)d_in[0];   // [16,256,768] f32
    const float* k  = (const float*)d_in[1];   // [32,256,768] f32
    const float* ls = (const float*)d_in[2];   // scalar
    const float* ar = (const float*)d_in[3];   // scalar
    const int* qm   = (const int*)d_in[4];     // [16,256]
    const int* km   = (const int*)d_in[5];     // [32,256]
    float* out      = (float*)d_out;           // [16,32] f32

    unsigned short* qn = (unsigned short*)d_ws;            // 16*256*768 bf16
    unsigned short* kn = qn + (size_t)BQ * SEQ * HD;       // 32*256*768 bf16

    // size grid to guaranteed co-residency (cooperative validation passes by
    // construction); persistent loops absorb any grid size. MI355X: 256 CUs.
    int bpc = 0;
    hipOccupancyMaxActiveBlocksPerMultiprocessor(&bpc, fused_kernel, 256, 0);
    if (bpc < 1) bpc = 1;
    int nblocks = bpc * 256;
    if (nblocks > NUNITS) nblocks = NUNITS;

    void* args[] = {(void*)&q, (void*)&k, (void*)&ls, (void*)&ar,
                    (void*)&qm, (void*)&km, (void*)&qn, (void*)&kn,
                    (void*)&out, (void*)&nblocks};
    hipLaunchCooperativeKernel((const void*)fused_kernel, dim3(nblocks),
                               dim3(256), args, 0, stream);
}